// Round 1
// baseline (1237.056 us; speedup 1.0000x reference)
//
#include <hip/hip_runtime.h>

// WeightOnlyInt4Linear: out[8192,11008] = x[8192,4096] @ dequant(packed_weight)
// Strategy: (1) x -> bf16, (2) W int4 -> bf16 stored [N][K] (transposed),
// (3) m97-structure bf16 MFMA GEMM (128x128 tile, BK=32, global_load_lds w16).

#define M_DIM 8192
#define K_DIM 4096
#define N_DIM 11008

typedef unsigned short u16;
typedef __bf16 bf16x8 __attribute__((ext_vector_type(8)));
typedef float floatx4 __attribute__((ext_vector_type(4)));
typedef u16 u16x8 __attribute__((ext_vector_type(8)));
typedef u16 u16x4 __attribute__((ext_vector_type(4)));

typedef __attribute__((address_space(1))) const void* gcvp;
typedef __attribute__((address_space(3))) void* svp;

static __device__ __forceinline__ u16 f2b(float f) {
  union { float f; unsigned u; } v;
  v.f = f;
  unsigned r = v.u + 0x7FFFu + ((v.u >> 16) & 1u);  // RNE, inputs are finite
  return (u16)(r >> 16);
}

// ---------------- kernel 1: x f32 -> bf16 ----------------
__global__ __launch_bounds__(256) void cvt_x_kernel(const float* __restrict__ x,
                                                    u16* __restrict__ xb) {
  int i = blockIdx.x * 256 + threadIdx.x;
  const int n4 = (M_DIM * K_DIM) / 4;   // 8,388,608 float4s
  const int stride = 2048 * 256;
  for (; i < n4; i += stride) {
    const float4 v = reinterpret_cast<const float4*>(x)[i];
    u16x4 r;
    r[0] = f2b(v.x); r[1] = f2b(v.y); r[2] = f2b(v.z); r[3] = f2b(v.w);
    reinterpret_cast<u16x4*>(xb)[i] = r;
  }
}

// ---------------- kernel 2: int4 W -> bf16 W^T [N][K] ----------------
// packed_weight[kw][o], kw in [0,512): word holds k = kw*8+j (little-endian nibbles).
// group g = k/128 = kw/16 (constant per word). w = (q - z) * s.
// Block: 64 o x 64 kw. Loads coalesced along o; LDS transpose; 16B stores along k.
__global__ __launch_bounds__(256) void dequant_w_kernel(const int* __restrict__ pw,
                                                        const float* __restrict__ sc,
                                                        const float* __restrict__ zr,
                                                        u16* __restrict__ wbt) {
  __shared__ int tile[64][65];  // +1 pad: phase-2 reads column-constant, kw-varying
  const int t = threadIdx.x;
  const int o0 = blockIdx.x * 64;
  const int kw0 = blockIdx.y * 64;
#pragma unroll
  for (int r = 0; r < 16; ++r) {
    const int kw = r * 4 + (t >> 6);
    const int o = t & 63;
    tile[kw][o] = pw[(kw0 + kw) * N_DIM + o0 + o];
  }
  __syncthreads();
  const int kwl = t & 63;
  const int g = (kw0 + kwl) >> 4;
  const int obase = (t >> 6) * 16;
  for (int it = 0; it < 16; ++it) {
    const int ol = obase + it;
    const int o = o0 + ol;
    const float s = sc[o * 32 + g];
    const float z = zr[o * 32 + g];
    const float b = -z * s;
    const int word = tile[kwl][ol];
    u16x8 r;
#pragma unroll
    for (int j = 0; j < 8; ++j) {
      const float q = (float)((word >> (4 * j)) & 0xF);
      r[j] = f2b(fmaf(q, s, b));
    }
    // 16B store; consecutive lanes (kwl) -> consecutive 16B: coalesced 1KB/wave
    *reinterpret_cast<u16x8*>(&wbt[(size_t)o * K_DIM + (size_t)(kw0 + kwl) * 8]) = r;
  }
}

// ---------------- kernel 3: bf16 MFMA GEMM (m97 structure) ----------------
// A = xb [M][K] bf16, B = wbt [N][K] bf16 (transposed), C = out [M][N] f32.
// 128x128 tile, BK=32, 256 thr (4 waves 2x2), 4x4 frags of 16x16x32 per wave.
__global__ __launch_bounds__(256) void gemm_kernel(const u16* __restrict__ xb,
                                                   const u16* __restrict__ wbt,
                                                   float* __restrict__ out) {
  __shared__ __align__(16) u16 As[128 * 32];  // [row m][k], linear for global_load_lds
  __shared__ __align__(16) u16 Bs[128 * 32];  // [row n][k]

  const int tid = threadIdx.x;
  const int w = tid >> 6;
  const int l = tid & 63;

  // bijective XCD swizzle: nwg = 5504 = 8 * 688
  const int bid = blockIdx.x;
  const int wg = (bid & 7) * 688 + (bid >> 3);
  const int NT = N_DIM / 128;  // 86
  const int mt = wg / NT, nt = wg % NT;
  const int m0 = mt * 128, n0 = nt * 128;

  const int lrow = l & 15;
  const int lk = (l >> 4) * 8;
  const int wr = (w >> 1) * 64;  // wave row offset in tile
  const int wc = (w & 1) * 64;   // wave col offset in tile

  floatx4 acc[4][4] = {};

  // staging: chunk c = i*256 + tid; row = c>>2 (4x 16B chunks per 32-elem row)
  const u16* ag = xb + (size_t)(m0 + (tid >> 2)) * K_DIM + (tid & 3) * 8;
  const u16* ag2 = xb + (size_t)(m0 + 64 + (tid >> 2)) * K_DIM + (tid & 3) * 8;
  const u16* bg = wbt + (size_t)(n0 + (tid >> 2)) * K_DIM + (tid & 3) * 8;
  const u16* bg2 = wbt + (size_t)(n0 + 64 + (tid >> 2)) * K_DIM + (tid & 3) * 8;
  // wave-uniform LDS bases (HW adds lane*16B)
  u16* asl = &As[(w * 64) * 8];
  u16* asl2 = &As[(256 + w * 64) * 8];
  u16* bsl = &Bs[(w * 64) * 8];
  u16* bsl2 = &Bs[(256 + w * 64) * 8];

  for (int kt = 0; kt < K_DIM / 32; ++kt) {
    const int koff = kt * 32;
    __syncthreads();  // previous compute done before overwriting LDS
    __builtin_amdgcn_global_load_lds(gcvp(ag + koff), svp(asl), 16, 0, 0);
    __builtin_amdgcn_global_load_lds(gcvp(ag2 + koff), svp(asl2), 16, 0, 0);
    __builtin_amdgcn_global_load_lds(gcvp(bg + koff), svp(bsl), 16, 0, 0);
    __builtin_amdgcn_global_load_lds(gcvp(bg2 + koff), svp(bsl2), 16, 0, 0);
    __syncthreads();  // compiler emits vmcnt(0) drain before barrier

    bf16x8 af[4], bfr[4];
#pragma unroll
    for (int mi = 0; mi < 4; ++mi)
      af[mi] = *reinterpret_cast<const bf16x8*>(&As[(wr + mi * 16 + lrow) * 32 + lk]);
#pragma unroll
    for (int ni = 0; ni < 4; ++ni)
      bfr[ni] = *reinterpret_cast<const bf16x8*>(&Bs[(wc + ni * 16 + lrow) * 32 + lk]);
#pragma unroll
    for (int mi = 0; mi < 4; ++mi)
#pragma unroll
      for (int ni = 0; ni < 4; ++ni)
        acc[mi][ni] =
            __builtin_amdgcn_mfma_f32_16x16x32_bf16(af[mi], bfr[ni], acc[mi][ni], 0, 0, 0);
  }

  // epilogue: C/D layout col = lane&15, row = (lane>>4)*4 + j  [verified m89/m91]
  const int orow = m0 + wr + (l >> 4) * 4;
  const int ocol = n0 + wc + lrow;
#pragma unroll
  for (int mi = 0; mi < 4; ++mi)
#pragma unroll
    for (int j = 0; j < 4; ++j) {
      float* op = out + (size_t)(orow + mi * 16 + j) * N_DIM + ocol;
#pragma unroll
      for (int ni = 0; ni < 4; ++ni) op[ni * 16] = acc[mi][ni][j];
    }
}

// ---------------- fallback (only if d_ws too small): fly-dequant, correct-first ----------------
__global__ __launch_bounds__(256) void gemm_naive(const float* __restrict__ x,
                                                  const int* __restrict__ pw,
                                                  const float* __restrict__ sc,
                                                  const float* __restrict__ zr,
                                                  float* __restrict__ out) {
  const int idx = blockIdx.x * 256 + threadIdx.x;
  if (idx >= M_DIM * N_DIM) return;
  const int m = idx / N_DIM, o = idx % N_DIM;
  const float* xr = x + (size_t)m * K_DIM;
  float acc = 0.f;
  for (int g = 0; g < 32; ++g) {
    const float s = sc[o * 32 + g];
    const float z = zr[o * 32 + g];
    const float b = -z * s;
    for (int kw = g * 16; kw < g * 16 + 16; ++kw) {
      const int word = pw[kw * N_DIM + o];
#pragma unroll
      for (int j = 0; j < 8; ++j) {
        const float q = (float)((word >> (4 * j)) & 0xF);
        acc += xr[kw * 8 + j] * fmaf(q, s, b);
      }
    }
  }
  out[idx] = acc;
}

extern "C" void kernel_launch(void* const* d_in, const int* in_sizes, int n_in,
                              void* d_out, int out_size, void* d_ws, size_t ws_size,
                              hipStream_t stream) {
  (void)in_sizes; (void)n_in; (void)out_size;
  const float* x = (const float*)d_in[0];
  const int* pw = (const int*)d_in[1];
  const float* sc = (const float*)d_in[2];
  const float* zr = (const float*)d_in[3];
  float* out = (float*)d_out;

  const size_t need = ((size_t)M_DIM * K_DIM + (size_t)N_DIM * K_DIM) * 2;  // 157,286,400 B
  if (ws_size >= need) {
    u16* xb = (u16*)d_ws;
    u16* wbt = xb + (size_t)M_DIM * K_DIM;
    cvt_x_kernel<<<2048, 256, 0, stream>>>(x, xb);
    dequant_w_kernel<<<dim3(N_DIM / 64, (K_DIM / 8) / 64), 256, 0, stream>>>(pw, sc, zr, wbt);
    gemm_kernel<<<(M_DIM / 128) * (N_DIM / 128), 256, 0, stream>>>(xb, wbt, out);
  } else {
    gemm_naive<<<(M_DIM * N_DIM + 255) / 256, 256, 0, stream>>>(x, pw, sc, zr, out);
  }
}

// Round 2
// 787.288 us; speedup vs baseline: 1.5713x; 1.5713x over previous
//
#include <hip/hip_runtime.h>

// WeightOnlyInt4Linear: out[8192,11008] = x[8192,4096] @ dequant(packed int4 W)
// (1) x -> bf16, (2) W int4 -> bf16 [N][K] transposed, (3) 256x256 deep-pipelined
// bf16 MFMA GEMM: BK=64, 8 waves, counted vmcnt, T2 XOR-swizzle, T5 setprio.

#define M_DIM 8192
#define K_DIM 4096
#define N_DIM 11008
#define BM 256
#define BN 256
#define BK 64
#define NKT (K_DIM / BK)  // 64

typedef unsigned short u16;
typedef __bf16 bf16x8 __attribute__((ext_vector_type(8)));
typedef float floatx4 __attribute__((ext_vector_type(4)));
typedef u16 u16x8 __attribute__((ext_vector_type(8)));
typedef u16 u16x4 __attribute__((ext_vector_type(4)));

typedef __attribute__((address_space(1))) const void* gcvp;
typedef __attribute__((address_space(3))) void* svp;

static __device__ __forceinline__ u16 f2b(float f) {
  union { float f; unsigned u; } v;
  v.f = f;
  unsigned r = v.u + 0x7FFFu + ((v.u >> 16) & 1u);  // RNE, finite inputs
  return (u16)(r >> 16);
}

// ---------------- kernel 1: x f32 -> bf16 ----------------
__global__ __launch_bounds__(256) void cvt_x_kernel(const float* __restrict__ x,
                                                    u16* __restrict__ xb) {
  int i = blockIdx.x * 256 + threadIdx.x;
  const int n4 = (M_DIM * K_DIM) / 4;
  const int stride = 2048 * 256;
  for (; i < n4; i += stride) {
    const float4 v = reinterpret_cast<const float4*>(x)[i];
    u16x4 r;
    r[0] = f2b(v.x); r[1] = f2b(v.y); r[2] = f2b(v.z); r[3] = f2b(v.w);
    reinterpret_cast<u16x4*>(xb)[i] = r;
  }
}

// ---------------- kernel 2: int4 W -> bf16 W^T [N][K] ----------------
__global__ __launch_bounds__(256) void dequant_w_kernel(const int* __restrict__ pw,
                                                        const float* __restrict__ sc,
                                                        const float* __restrict__ zr,
                                                        u16* __restrict__ wbt) {
  __shared__ int tile[64][65];
  const int t = threadIdx.x;
  const int o0 = blockIdx.x * 64;
  const int kw0 = blockIdx.y * 64;
#pragma unroll
  for (int r = 0; r < 16; ++r) {
    const int kw = r * 4 + (t >> 6);
    const int o = t & 63;
    tile[kw][o] = pw[(kw0 + kw) * N_DIM + o0 + o];
  }
  __syncthreads();
  const int kwl = t & 63;
  const int g = (kw0 + kwl) >> 4;
  const int obase = (t >> 6) * 16;
  for (int it = 0; it < 16; ++it) {
    const int ol = obase + it;
    const int o = o0 + ol;
    const float s = sc[o * 32 + g];
    const float z = zr[o * 32 + g];
    const float b = -z * s;
    const int word = tile[kwl][ol];
    u16x8 r;
#pragma unroll
    for (int j = 0; j < 8; ++j) {
      const float q = (float)((word >> (4 * j)) & 0xF);
      r[j] = f2b(fmaf(q, s, b));
    }
    *reinterpret_cast<u16x8*>(&wbt[(size_t)o * K_DIM + (size_t)(kw0 + kwl) * 8]) = r;
  }
}

// ---------------- kernel 3: 256x256 deep-pipelined bf16 MFMA GEMM ----------------
// A = xb [M][K], B = wbt [N][K], C = out [M][N] f32.
// 512 thr = 8 waves (2 M x 4 N); per wave 128x64 out = 8x4 frags of 16x16x32.
// LDS: 2 buf x (A[256][64] + B[256][64]) = 128 KiB, 16B-slot XOR swizzle (row&7).

#define WAITL(n)                                              \
  asm volatile("s_waitcnt lgkmcnt(" #n ")" ::: "memory");     \
  __builtin_amdgcn_sched_barrier(0)
#define WAITV(n)                                              \
  asm volatile("s_waitcnt vmcnt(" #n ")" ::: "memory");       \
  __builtin_amdgcn_sched_barrier(0)

__global__ __launch_bounds__(512, 2) void gemm_kernel(const u16* __restrict__ xb,
                                                      const u16* __restrict__ wbt,
                                                      float* __restrict__ out) {
  __shared__ __align__(16) u16 lds[2][2][BM * BK];  // 131072 B

  const int tid = threadIdx.x;
  const int w = tid >> 6;
  const int l = tid & 63;
  const int wm = w >> 2;  // 0..1
  const int wn = w & 3;   // 0..3

  // bijective XCD swizzle: 1376 = 8*172
  const int bid = blockIdx.x;
  const int wg = (bid & 7) * 172 + (bid >> 3);
  const int NT = N_DIM / BN;  // 43
  const int m0 = (wg / NT) * BM;
  const int n0 = (wg % NT) * BN;

  // ---- staging addresses: chunk c=j*512+tid, row=c>>3, slot=c&7 (16B slots) ----
  // linear LDS dest + inverse-swizzled global source (involution: slot ^ (row&7))
  const int r0 = tid >> 3;  // row for j=0 (rows j*64+r0)
  const int scc = ((tid & 7) ^ (r0 & 7)) * 8;
  const u16* srcA0 = xb + (size_t)(m0 + r0) * K_DIM + scc;
  const u16* srcB0 = wbt + (size_t)(n0 + r0) * K_DIM + scc;

#define STAGE(buf, kt)                                                              \
  do {                                                                              \
    const int _ko = (kt) * BK;                                                      \
    _Pragma("unroll")                                                               \
    for (int _j = 0; _j < 4; ++_j) {                                                \
      __builtin_amdgcn_global_load_lds(gcvp(srcA0 + (size_t)_j * 64 * K_DIM + _ko), \
          svp(&lds[buf][0][(_j * 512 + w * 64) * 8]), 16, 0, 0);                    \
      __builtin_amdgcn_global_load_lds(gcvp(srcB0 + (size_t)_j * 64 * K_DIM + _ko), \
          svp(&lds[buf][1][(_j * 512 + w * 64) * 8]), 16, 0, 0);                    \
    }                                                                               \
  } while (0)

  // ---- fragment read bases (element offsets); swizzled read side ----
  // A frag (mi,kk): row = wm*128 + mi*16 + (l&15); slot = kk*4 + (l>>4); slot ^= row&7
  // row&7 == l&7 (mi*16, wm*128 are 0 mod 8) -> base + mi*1024 (+^32 for kk=1)
  const int swz = (((l >> 4) ^ (l & 7)) * 8);
  const int baseA_k0 = (wm * 128 + (l & 15)) * 64 + swz;
  const int baseA_k1 = baseA_k0 ^ 32;
  const int baseB_k0 = (wn * 64 + (l & 15)) * 64 + swz;
  const int baseB_k1 = baseB_k0 ^ 32;
  const u16* lp = &lds[0][0][0];

#define LOADFRAGS(AF, BF, ab, bb)                                     \
  do {                                                                \
    _Pragma("unroll")                                                 \
    for (int _mi = 0; _mi < 8; ++_mi)                                 \
      (AF)[_mi] = *reinterpret_cast<const bf16x8*>(&lp[(ab) + _mi * 1024]); \
    _Pragma("unroll")                                                 \
    for (int _ni = 0; _ni < 4; ++_ni)                                 \
      (BF)[_ni] = *reinterpret_cast<const bf16x8*>(&lp[(bb) + _ni * 1024]); \
  } while (0)

  floatx4 acc[8][4] = {};

#define MFMA32(AF, BF)                                                          \
  do {                                                                          \
    __builtin_amdgcn_s_setprio(1);                                              \
    _Pragma("unroll")                                                           \
    for (int _m = 0; _m < 8; ++_m)                                              \
      _Pragma("unroll")                                                         \
      for (int _n = 0; _n < 4; ++_n)                                            \
        acc[_m][_n] = __builtin_amdgcn_mfma_f32_16x16x32_bf16((AF)[_m], (BF)[_n], \
                                                              acc[_m][_n], 0, 0, 0); \
    __builtin_amdgcn_s_setprio(0);                                              \
  } while (0)

  bf16x8 af0[8], bf0[4], af1[8], bf1[4];
  int cur = 0;

  // ---- prologue: stage tiles 0,1; wait tile 0; read its kk0 frags ----
  STAGE(0, 0);
  STAGE(1, 1);
  WAITV(8);
  __builtin_amdgcn_s_barrier();
  LOADFRAGS(af0, bf0, baseA_k0, 16384 + baseB_k0);

  // ---- main loop: 2 barriers / K-tile, counted vmcnt(8), stage-early ----
  for (int t = 0; t < NKT - 2; ++t) {
    const int cb = cur * 32768;
    // P1: issue kk1 reads; MFMA kk0; finish all reads of buf[cur]; barrier
    LOADFRAGS(af1, bf1, cb + baseA_k1, cb + 16384 + baseB_k1);
    WAITL(12);
    MFMA32(af0, bf0);
    WAITL(0);
    __builtin_amdgcn_s_barrier();
    // P2: stage t+2 into buf[cur]; MFMA kk1; wait tile t+1 landed; barrier
    STAGE(cur, t + 2);
    __builtin_amdgcn_sched_barrier(0);
    MFMA32(af1, bf1);
    WAITV(8);
    __builtin_amdgcn_s_barrier();
    cur ^= 1;
    // P3: read kk0 frags of tile t+1
    const int cb2 = cur * 32768;
    LOADFRAGS(af0, bf0, cb2 + baseA_k0, cb2 + 16384 + baseB_k0);
  }
  // ---- peel t = NKT-2 ----
  {
    const int cb = cur * 32768;
    LOADFRAGS(af1, bf1, cb + baseA_k1, cb + 16384 + baseB_k1);
    WAITL(12);
    MFMA32(af0, bf0);
    WAITL(0);
    __builtin_amdgcn_s_barrier();
    MFMA32(af1, bf1);
    WAITV(0);
    __builtin_amdgcn_s_barrier();
    cur ^= 1;
    const int cb2 = cur * 32768;
    LOADFRAGS(af0, bf0, cb2 + baseA_k0, cb2 + 16384 + baseB_k0);
  }
  // ---- peel t = NKT-1 ----
  {
    const int cb = cur * 32768;
    LOADFRAGS(af1, bf1, cb + baseA_k1, cb + 16384 + baseB_k1);
    WAITL(12);
    MFMA32(af0, bf0);
    WAITL(0);
    MFMA32(af1, bf1);
  }

  // ---- epilogue: C/D map col = l&15, row = (l>>4)*4 + j (verified R1) ----
  const int orow0 = m0 + wm * 128 + (l >> 4) * 4;
  const int ocol0 = n0 + wn * 64 + (l & 15);
#pragma unroll
  for (int mi = 0; mi < 8; ++mi)
#pragma unroll
    for (int j = 0; j < 4; ++j) {
      float* op = out + (size_t)(orow0 + mi * 16 + j) * N_DIM + ocol0;
#pragma unroll
      for (int ni = 0; ni < 4; ++ni) op[ni * 16] = acc[mi][ni][j];
    }
}

// ---------------- fallback: fly-dequant (ws too small) ----------------
__global__ __launch_bounds__(256) void gemm_naive(const float* __restrict__ x,
                                                  const int* __restrict__ pw,
                                                  const float* __restrict__ sc,
                                                  const float* __restrict__ zr,
                                                  float* __restrict__ out) {
  const int idx = blockIdx.x * 256 + threadIdx.x;
  if (idx >= M_DIM * N_DIM) return;
  const int m = idx / N_DIM, o = idx % N_DIM;
  const float* xr = x + (size_t)m * K_DIM;
  float acc = 0.f;
  for (int g = 0; g < 32; ++g) {
    const float s = sc[o * 32 + g];
    const float z = zr[o * 32 + g];
    const float b = -z * s;
    for (int kw = g * 16; kw < g * 16 + 16; ++kw) {
      const int word = pw[kw * N_DIM + o];
#pragma unroll
      for (int j = 0; j < 8; ++j) {
        const float q = (float)((word >> (4 * j)) & 0xF);
        acc += xr[kw * 8 + j] * fmaf(q, s, b);
      }
    }
  }
  out[idx] = acc;
}

extern "C" void kernel_launch(void* const* d_in, const int* in_sizes, int n_in,
                              void* d_out, int out_size, void* d_ws, size_t ws_size,
                              hipStream_t stream) {
  (void)in_sizes; (void)n_in; (void)out_size;
  const float* x = (const float*)d_in[0];
  const int* pw = (const int*)d_in[1];
  const float* sc = (const float*)d_in[2];
  const float* zr = (const float*)d_in[3];
  float* out = (float*)d_out;

  const size_t need = ((size_t)M_DIM * K_DIM + (size_t)N_DIM * K_DIM) * 2;
  if (ws_size >= need) {
    u16* xb = (u16*)d_ws;
    u16* wbt = xb + (size_t)M_DIM * K_DIM;
    cvt_x_kernel<<<2048, 256, 0, stream>>>(x, xb);
    dequant_w_kernel<<<dim3(N_DIM / 64, (K_DIM / 8) / 64), 256, 0, stream>>>(pw, sc, zr, wbt);
    gemm_kernel<<<(M_DIM / BM) * (N_DIM / BN), 512, 0, stream>>>(xb, wbt, out);
  } else {
    gemm_naive<<<(M_DIM * N_DIM + 255) / 256, 256, 0, stream>>>(x, pw, sc, zr, out);
  }
}

// Round 4
// 736.639 us; speedup vs baseline: 1.6793x; 1.0688x over previous
//
#include <hip/hip_runtime.h>

// WeightOnlyInt4Linear: out[8192,11008] = x[8192,4096] @ dequant(packed int4 W)
// (1) x -> bf16, (2) W int4 -> bf16 [N][K] transposed, (3) 256x256 bf16 MFMA GEMM
// 8-phase schedule (4 phases/K-tile), counted vmcnt(6), T2 swizzle, T5 setprio.
// R4 fix: peeled last two K-tiles with progressive vmcnt drain 6->4->2->0
// (R3's conditional stages made WAITV(6) vacuous in the tail -> staging race).

#define M_DIM 8192
#define K_DIM 4096
#define N_DIM 11008
#define BM 256
#define BN 256
#define BK 64
#define NKT (K_DIM / BK)  // 64

typedef unsigned short u16;
typedef __bf16 bf16x8 __attribute__((ext_vector_type(8)));
typedef float floatx4 __attribute__((ext_vector_type(4)));
typedef u16 u16x8 __attribute__((ext_vector_type(8)));
typedef u16 u16x4 __attribute__((ext_vector_type(4)));

typedef __attribute__((address_space(1))) const void* gcvp;
typedef __attribute__((address_space(3))) void* svp;

static __device__ __forceinline__ u16 f2b(float f) {
  union { float f; unsigned u; } v;
  v.f = f;
  unsigned r = v.u + 0x7FFFu + ((v.u >> 16) & 1u);  // RNE, finite inputs
  return (u16)(r >> 16);
}

// ---------------- kernel 1: x f32 -> bf16 ----------------
__global__ __launch_bounds__(256) void cvt_x_kernel(const float* __restrict__ x,
                                                    u16* __restrict__ xb) {
  int i = blockIdx.x * 256 + threadIdx.x;
  const int n4 = (M_DIM * K_DIM) / 4;
  const int stride = 2048 * 256;
  for (; i < n4; i += stride) {
    const float4 v = reinterpret_cast<const float4*>(x)[i];
    u16x4 r;
    r[0] = f2b(v.x); r[1] = f2b(v.y); r[2] = f2b(v.z); r[3] = f2b(v.w);
    reinterpret_cast<u16x4*>(xb)[i] = r;
  }
}

// ---------------- kernel 2: int4 W -> bf16 W^T [N][K] ----------------
__global__ __launch_bounds__(256) void dequant_w_kernel(const int* __restrict__ pw,
                                                        const float* __restrict__ sc,
                                                        const float* __restrict__ zr,
                                                        u16* __restrict__ wbt) {
  __shared__ int tile[64][65];
  const int t = threadIdx.x;
  const int o0 = blockIdx.x * 64;
  const int kw0 = blockIdx.y * 64;
#pragma unroll
  for (int r = 0; r < 16; ++r) {
    const int kw = r * 4 + (t >> 6);
    const int o = t & 63;
    tile[kw][o] = pw[(kw0 + kw) * N_DIM + o0 + o];
  }
  __syncthreads();
  const int kwl = t & 63;
  const int g = (kw0 + kwl) >> 4;
  const int obase = (t >> 6) * 16;
  for (int it = 0; it < 16; ++it) {
    const int ol = obase + it;
    const int o = o0 + ol;
    const float s = sc[o * 32 + g];
    const float z = zr[o * 32 + g];
    const float b = -z * s;
    const int word = tile[kwl][ol];
    u16x8 r;
#pragma unroll
    for (int j = 0; j < 8; ++j) {
      const float q = (float)((word >> (4 * j)) & 0xF);
      r[j] = f2b(fmaf(q, s, b));
    }
    *reinterpret_cast<u16x8*>(&wbt[(size_t)o * K_DIM + (size_t)(kw0 + kwl) * 8]) = r;
  }
}

// ---------------- kernel 3: 256x256 8-phase bf16 MFMA GEMM ----------------
// 512 thr = 8 waves (2M x 4N); per wave 128x64 out = 8x4 frags of 16x16x32.
// LDS: 2 buf x (A[256][64] + B[256][64]) bf16 = 128 KiB, 16B-slot swizzle ^(row&7).

#define WAITL0                                               \
  asm volatile("s_waitcnt lgkmcnt(0)" ::: "memory");         \
  __builtin_amdgcn_sched_barrier(0)
#define WAITV(n)                                             \
  asm volatile("s_waitcnt vmcnt(" #n ")" ::: "memory");      \
  __builtin_amdgcn_sched_barrier(0)
#define BAR __builtin_amdgcn_s_barrier()

__global__ __launch_bounds__(512, 2) void gemm_kernel(const u16* __restrict__ xb,
                                                      const u16* __restrict__ wbt,
                                                      float* __restrict__ out) {
  __shared__ __align__(16) u16 lds[2][2][BM * BK];  // 131072 B

  const int tid = threadIdx.x;
  const int w = tid >> 6;
  const int l = tid & 63;
  const int wm = w >> 2;  // 0..1
  const int wn = w & 3;   // 0..3

  // bijective XCD swizzle: 1376 = 8*172
  const int bid = blockIdx.x;
  const int wg = (bid & 7) * 172 + (bid >> 3);
  const int NT = N_DIM / BN;  // 43
  const int m0 = (wg / NT) * BM;
  const int n0 = (wg % NT) * BN;

  // ---- staging: quarter (64 rows x 64 cols); thread -> row=q*64+(tid>>3), slot=tid&7
  // linear LDS dest (wave base + lane*16B), inverse-swizzled global src col.
  const int sr = tid >> 3;                       // 0..63
  const int scc = ((tid & 7) ^ (sr & 7)) * 8;    // involution slot^(row&7)
  const u16* srcA = xb + (size_t)(m0 + sr) * K_DIM + scc;
  const u16* srcB = wbt + (size_t)(n0 + sr) * K_DIM + scc;

#define STAGEQ(buf, op, q, t)                                                  \
  __builtin_amdgcn_global_load_lds(                                            \
      gcvp(((op) ? srcB : srcA) + (size_t)((q) * 64) * K_DIM + (t) * 64),      \
      svp(&lds[buf][op][((q) * 64 + w * 8) * 64]), 16, 0, 0)

  // ---- fragment bases (elem offsets, swizzled read side); kk=1 addr = kk=0 ^ 32
  const int swz = ((l >> 4) ^ (l & 7)) * 8;
  const int baseA = (wm * 128 + (l & 15)) * 64 + swz;
  const int baseB = 16384 + (wn * 64 + (l & 15)) * 64 + swz;
  const u16* lp = &lds[0][0][0];

  bf16x8 a[4][2], b0[2][2], b1[2][2];

#define LDA(cb, S)                                                                      \
  do {                                                                                  \
    _Pragma("unroll") for (int _m = 0; _m < 4; ++_m) {                                  \
      const int _e = (cb) + baseA + ((S) * 4 + _m) * 1024;                              \
      a[_m][0] = *reinterpret_cast<const bf16x8*>(&lp[_e]);                             \
      a[_m][1] = *reinterpret_cast<const bf16x8*>(&lp[_e ^ 32]);                        \
    }                                                                                   \
  } while (0)
#define LDB(cb, BA, U)                                                                  \
  do {                                                                                  \
    _Pragma("unroll") for (int _n = 0; _n < 2; ++_n) {                                  \
      const int _e = (cb) + baseB + ((U) * 2 + _n) * 1024;                              \
      BA[_n][0] = *reinterpret_cast<const bf16x8*>(&lp[_e]);                            \
      BA[_n][1] = *reinterpret_cast<const bf16x8*>(&lp[_e ^ 32]);                       \
    }                                                                                   \
  } while (0)

  floatx4 acc[8][4] = {};

#define QMFMA(S, BA, U)                                                                 \
  do {                                                                                  \
    __builtin_amdgcn_s_setprio(1);                                                     \
    _Pragma("unroll") for (int _m = 0; _m < 4; ++_m)                                    \
      _Pragma("unroll") for (int _n = 0; _n < 2; ++_n)                                  \
        _Pragma("unroll") for (int _k = 0; _k < 2; ++_k)                                \
          acc[(S) * 4 + _m][(U) * 2 + _n] = __builtin_amdgcn_mfma_f32_16x16x32_bf16(    \
              a[_m][_k], BA[_n][_k], acc[(S) * 4 + _m][(U) * 2 + _n], 0, 0, 0);         \
    __builtin_amdgcn_s_setprio(0);                                                     \
  } while (0)

  // ---- prologue: tile0 fully, tile1 A q0-q3 + B q0,q1 (14 loads; oldest 8 = tile0)
  STAGEQ(0, 0, 0, 0); STAGEQ(0, 0, 1, 0); STAGEQ(0, 0, 2, 0); STAGEQ(0, 0, 3, 0);
  STAGEQ(0, 1, 0, 0); STAGEQ(0, 1, 1, 0); STAGEQ(0, 1, 2, 0); STAGEQ(0, 1, 3, 0);
  STAGEQ(1, 0, 0, 1); STAGEQ(1, 0, 1, 1); STAGEQ(1, 0, 2, 1); STAGEQ(1, 0, 3, 1);
  STAGEQ(1, 1, 0, 1); STAGEQ(1, 1, 1, 1);
  WAITV(6);
  BAR;

  // ---- main loop: 4 phases / K-tile, all stages unconditional, t in [0, NKT-3] ----
  // vmcnt ledger (per wave, 2 issues + WAITV(6) per phase => retires oldest 2):
  // tile T loads issued: A0,A2 @(T-2)p1; B0,B1 @(T-2)p2; A1,A3 @(T-2)p3; B2,B3 @(T-1)p0
  // tile T loads retired: A0,A2 @(T-1)p1... B2,B3 @(T-1)p3  => all landed before T p0.
#pragma unroll 2
  for (int t = 0; t < NKT - 2; ++t) {
    const int buf = t & 1;
    const int sb = buf ^ 1;
    const int cb = buf * 32768;
    // phase 0: read A-sub0 + B-sub0 of tile t; stage B-q2,q3[t+1]
    LDA(cb, 0);
    LDB(cb, b0, 0);
    STAGEQ(sb, 1, 2, t + 1); STAGEQ(sb, 1, 3, t + 1);
    WAITV(6); BAR; WAITL0;
    QMFMA(0, b0, 0);
    BAR;
    // phase 1: read B-sub1; stage A-q0,q2[t+2] (A[t] q0,q2 dead after p0)
    LDB(cb, b1, 1);
    STAGEQ(buf, 0, 0, t + 2); STAGEQ(buf, 0, 2, t + 2);
    WAITV(6); BAR; WAITL0;
    QMFMA(0, b1, 1);
    BAR;
    // phase 2: read A-sub1; stage B-q0,q1[t+2] (B[t] dead after p1)
    LDA(cb, 1);
    STAGEQ(buf, 1, 0, t + 2); STAGEQ(buf, 1, 1, t + 2);
    WAITV(6); BAR; WAITL0;
    QMFMA(1, b0, 0);
    BAR;
    // phase 3: stage A-q1,q3[t+2] (A[t] q1,q3 dead after p2)
    STAGEQ(buf, 0, 1, t + 2); STAGEQ(buf, 0, 3, t + 2);
    WAITV(6); BAR;
    QMFMA(1, b1, 1);
    BAR;
  }

  // ---- peel t = NKT-2 (buf=0): progressive drain of tile NKT-1's loads ----
  {
    const int cb = 0;
    LDA(cb, 0);
    LDB(cb, b0, 0);
    STAGEQ(1, 1, 2, NKT - 1); STAGEQ(1, 1, 3, NKT - 1);
    WAITV(6); BAR; WAITL0;   // retires A0,A2[NKT-1]
    QMFMA(0, b0, 0);
    BAR;
    LDB(cb, b1, 1);
    WAITV(4); BAR; WAITL0;   // retires B0,B1[NKT-1]
    QMFMA(0, b1, 1);
    BAR;
    LDA(cb, 1);
    WAITV(2); BAR; WAITL0;   // retires A1,A3[NKT-1]
    QMFMA(1, b0, 0);
    BAR;
    WAITV(0); BAR;           // retires B2,B3[NKT-1]; barrier publishes to all waves
    QMFMA(1, b1, 1);
    BAR;
  }
  // ---- peel t = NKT-1 (buf=1): all landed, no stages, no barriers needed ----
  {
    const int cb = 32768;
    LDA(cb, 0);
    LDB(cb, b0, 0);
    WAITL0;
    QMFMA(0, b0, 0);
    LDB(cb, b1, 1);
    WAITL0;
    QMFMA(0, b1, 1);
    LDA(cb, 1);
    WAITL0;
    QMFMA(1, b0, 0);
    QMFMA(1, b1, 1);
  }

  // ---- epilogue: C/D map col = l&15, row = (l>>4)*4 + j (verified R1/R2) ----
  const int orow0 = m0 + wm * 128 + (l >> 4) * 4;
  const int ocol0 = n0 + wn * 64 + (l & 15);
#pragma unroll
  for (int mi = 0; mi < 8; ++mi)
#pragma unroll
    for (int j = 0; j < 4; ++j) {
      float* op = out + (size_t)(orow0 + mi * 16 + j) * N_DIM + ocol0;
#pragma unroll
      for (int ni = 0; ni < 4; ++ni) op[ni * 16] = acc[mi][ni][j];
    }
}

// ---------------- fallback: fly-dequant (ws too small) ----------------
__global__ __launch_bounds__(256) void gemm_naive(const float* __restrict__ x,
                                                  const int* __restrict__ pw,
                                                  const float* __restrict__ sc,
                                                  const float* __restrict__ zr,
                                                  float* __restrict__ out) {
  const int idx = blockIdx.x * 256 + threadIdx.x;
  if (idx >= M_DIM * N_DIM) return;
  const int m = idx / N_DIM, o = idx % N_DIM;
  const float* xr = x + (size_t)m * K_DIM;
  float acc = 0.f;
  for (int g = 0; g < 32; ++g) {
    const float s = sc[o * 32 + g];
    const float z = zr[o * 32 + g];
    const float b = -z * s;
    for (int kw = g * 16; kw < g * 16 + 16; ++kw) {
      const int word = pw[kw * N_DIM + o];
#pragma unroll
      for (int j = 0; j < 8; ++j) {
        const float q = (float)((word >> (4 * j)) & 0xF);
        acc += xr[kw * 8 + j] * fmaf(q, s, b);
      }
    }
  }
  out[idx] = acc;
}

extern "C" void kernel_launch(void* const* d_in, const int* in_sizes, int n_in,
                              void* d_out, int out_size, void* d_ws, size_t ws_size,
                              hipStream_t stream) {
  (void)in_sizes; (void)n_in; (void)out_size;
  const float* x = (const float*)d_in[0];
  const int* pw = (const int*)d_in[1];
  const float* sc = (const float*)d_in[2];
  const float* zr = (const float*)d_in[3];
  float* out = (float*)d_out;

  const size_t need = ((size_t)M_DIM * K_DIM + (size_t)N_DIM * K_DIM) * 2;
  if (ws_size >= need) {
    u16* xb = (u16*)d_ws;
    u16* wbt = xb + (size_t)M_DIM * K_DIM;
    cvt_x_kernel<<<2048, 256, 0, stream>>>(x, xb);
    dequant_w_kernel<<<dim3(N_DIM / 64, (K_DIM / 8) / 64), 256, 0, stream>>>(pw, sc, zr, wbt);
    gemm_kernel<<<(M_DIM / BM) * (N_DIM / BN), 512, 0, stream>>>(xb, wbt, out);
  } else {
    gemm_naive<<<(M_DIM * N_DIM + 255) / 256, 256, 0, stream>>>(x, pw, sc, zr, out);
  }
}